// Round 2
// baseline (599.853 us; speedup 1.0000x reference)
//
#include <hip/hip_runtime.h>

// ScalingAndSquaring: v <- v + warp(v), 7 steps, (2,3,160,160,160) f32.
// out(d,h,w) = v(d,h,w) + trilinear v(z~w, y~h, x~d)  (self-transposed gather).
// 32(d) x 32(w) tile per h-plane staged via LDS: global I/O is w-coalesced
// (float4), gathers run with d-fast lanes (x is the innermost storage axis
// -> lane-contiguous gather addresses). Round 2: full unroll of the 4
// sample-iterations for memory-level parallelism (was latency-bound at
// VALUBusy 32% / 27% HBM), float4 staging, nontemporal dst stores.

constexpr int SZ  = 160;
constexpr int HW  = SZ * SZ;          // 25600
constexpr int DHW = SZ * SZ * SZ;     // 4096000

typedef float vfloat4 __attribute__((ext_vector_type(4)));

__global__ __launch_bounds__(256, 4)
void warp_step_kernel(const float* __restrict__ src,
                      float* __restrict__ dst,
                      float inScale)
{
    // --- XCD-contiguous swizzle: 8000 blocks, 8 XCDs, 1000 contiguous each ---
    const int wg = (int)blockIdx.x;                 // 0..7999
    const int r  = (wg & 7) * 1000 + (wg >> 3);     // bijective (8000 % 8 == 0)
    const int h0  = r % SZ;                         // H-axis plane
    const int t   = r / SZ;                         // 0..49
    const int bat = t / 25;                         // batch
    const int tt  = t % 25;
    const int a0  = (tt % 5) * 32;                  // D-axis tile base
    const int c0  = (tt / 5) * 32;                  // W-axis tile base

    const float* __restrict__ vb = src + (size_t)bat * 3 * DHW;
    float*       __restrict__ db = dst + (size_t)bat * 3 * DHW;

    // tile[ch][w_local][d_local], stride 33 -> conflict-free in both phases
    __shared__ float tile[3][32][33];

    const int tid = (int)threadIdx.x;

    // --- phase 1: stage own-voxel v tile (scaled). float4 reads, 96 rows
    //     of 32 floats = 8 float4 each; thread t does quad (t&7) of row t>>3.
    {
        const int q  = (tid & 7) << 2;   // float4 start within row (w_local)
        const int r0 = tid >> 3;         // 0..31
        #pragma unroll
        for (int p = 0; p < 3; ++p) {
            const int row = r0 + (p << 5);           // 0..95 = ch*32 + a
            const int ch  = row >> 5;
            const int a   = row & 31;
            const vfloat4 vv = *reinterpret_cast<const vfloat4*>(
                &vb[ch * DHW + (a0 + a) * HW + h0 * SZ + c0 + q]);
            tile[ch][q + 0][a] = vv.x * inScale;
            tile[ch][q + 1][a] = vv.y * inScale;
            tile[ch][q + 2][a] = vv.z * inScale;
            tile[ch][q + 3][a] = vv.w * inScale;
        }
    }
    __syncthreads();

    // --- phase 2: d-fast lanes; gathers are x-contiguous per wave.
    //     Fully unrolled: 4 independent samples -> ~96 loads in flight.
    const int a  = tid & 31;      // d_local  (lane-fast)
    const int cb = tid >> 5;      // 0..7     (w_local base)
    const float gx = (float)(a0 + a);   // d feeds grid_sample's x slot
    const float gy = (float)h0;         // h feeds y slot

    #pragma unroll
    for (int i = 0; i < 4; ++i) {
        const int c = cb + (i << 3);    // w_local
        const float gz = (float)(c0 + c);   // w feeds z slot
        const float v0 = tile[0][c][a];
        const float v1 = tile[1][c][a];
        const float v2 = tile[2][c][a];

        // reference op sequence (incl. divide) to keep rounding close
        float ix = ((2.0f * ((gx + v0) / 159.0f - 0.5f) + 1.0f) * 160.0f - 1.0f) * 0.5f;
        float iy = ((2.0f * ((gy + v1) / 159.0f - 0.5f) + 1.0f) * 160.0f - 1.0f) * 0.5f;
        float iz = ((2.0f * ((gz + v2) / 159.0f - 0.5f) + 1.0f) * 160.0f - 1.0f) * 0.5f;
        ix = fminf(fmaxf(ix, 0.0f), 159.0f);
        iy = fminf(fmaxf(iy, 0.0f), 159.0f);
        iz = fminf(fmaxf(iz, 0.0f), 159.0f);

        const float fx = floorf(ix), fy = floorf(iy), fz = floorf(iz);
        const float wx = ix - fx,  wy = iy - fy,  wz = iz - fz;
        const int x0 = (int)fx, y0 = (int)fy, z0 = (int)fz;
        const int x1 = min(x0 + 1, SZ - 1);
        const int y1 = min(y0 + 1, SZ - 1);
        const int z1 = min(z0 + 1, SZ - 1);

        const int r00 = (z0 * SZ + y0) * SZ;
        const int r01 = (z0 * SZ + y1) * SZ;
        const int r10 = (z1 * SZ + y0) * SZ;
        const int r11 = (z1 * SZ + y1) * SZ;

        const float wy0 = 1.0f - wy, wz0 = 1.0f - wz;
        const float w00 = wz0 * wy0, w01 = wz0 * wy;
        const float w10 = wz  * wy0, w11 = wz  * wy;

        float res[3];
        #pragma unroll
        for (int ch = 0; ch < 3; ++ch) {
            const float* __restrict__ pc = vb + ch * DHW;
            const float l00 = pc[r00 + x0], h00 = pc[r00 + x1];
            const float l01 = pc[r01 + x0], h01 = pc[r01 + x1];
            const float l10 = pc[r10 + x0], h10 = pc[r10 + x1];
            const float l11 = pc[r11 + x0], h11 = pc[r11 + x1];
            const float s00 = l00 + wx * (h00 - l00);
            const float s01 = l01 + wx * (h01 - l01);
            const float s10 = l10 + wx * (h10 - l10);
            const float s11 = l11 + wx * (h11 - l11);
            res[ch] = (s00 * w00 + s01 * w01) + (s10 * w10 + s11 * w11);
        }
        // in-place: only this thread ever touches (c, a) slots
        tile[0][c][a] = v0 + res[0] * inScale;
        tile[1][c][a] = v1 + res[1] * inScale;
        tile[2][c][a] = v2 + res[2] * inScale;
    }
    __syncthreads();

    // --- phase 3: coalesced float4 nontemporal writes ---
    {
        const int q  = (tid & 7) << 2;
        const int r0 = tid >> 3;
        #pragma unroll
        for (int p = 0; p < 3; ++p) {
            const int row = r0 + (p << 5);
            const int ch  = row >> 5;
            const int a2  = row & 31;
            vfloat4 vv;
            vv.x = tile[ch][q + 0][a2];
            vv.y = tile[ch][q + 1][a2];
            vv.z = tile[ch][q + 2][a2];
            vv.w = tile[ch][q + 3][a2];
            __builtin_nontemporal_store(vv, reinterpret_cast<vfloat4*>(
                &db[ch * DHW + (a0 + a2) * HW + h0 * SZ + c0 + q]));
        }
    }
}

extern "C" void kernel_launch(void* const* d_in, const int* in_sizes, int n_in,
                              void* d_out, int out_size, void* d_ws, size_t ws_size,
                              hipStream_t stream)
{
    const float* vin = (const float*)d_in[0];
    float* out = (float*)d_out;
    float* ws  = (float*)d_ws;   // needs >= 2*3*160^3*4 = 98,304,000 bytes

    dim3 grid(8000), block(256);
    // 7 steps, ping-pong so the final result lands in d_out.
    warp_step_kernel<<<grid, block, 0, stream>>>(vin, out, 1.0f / 128.0f); // v1
    warp_step_kernel<<<grid, block, 0, stream>>>(out, ws,  1.0f);          // v2
    warp_step_kernel<<<grid, block, 0, stream>>>(ws,  out, 1.0f);          // v3
    warp_step_kernel<<<grid, block, 0, stream>>>(out, ws,  1.0f);          // v4
    warp_step_kernel<<<grid, block, 0, stream>>>(ws,  out, 1.0f);          // v5
    warp_step_kernel<<<grid, block, 0, stream>>>(out, ws,  1.0f);          // v6
    warp_step_kernel<<<grid, block, 0, stream>>>(ws,  out, 1.0f);          // v7
}

// Round 3
// 594.496 us; speedup vs baseline: 1.0090x; 1.0090x over previous
//
#include <hip/hip_runtime.h>

// ScalingAndSquaring: v <- v + warp(v), 7 steps, (2,3,160,160,160) f32.
// out(d,h,w) = v(d,h,w) + trilinear v(z~w, y~h, x~d)  (self-transposed gather).
// 32(d) x 32(w) tile per h-plane staged via LDS: global I/O is w-coalesced
// (float4), gathers run with d-fast lanes (x innermost -> contiguous).
// Round 3: phase 2 restructured into strict stages (all LDS reads -> all
// address math -> all 96 global loads -> interp -> one LDS write-back) so the
// compiler can keep all gathers in flight. Round 2 failed because interleaved
// LDS writes serialized the samples (VGPR fell to 28 = no MLP).

constexpr int SZ  = 160;
constexpr int HW  = SZ * SZ;          // 25600
constexpr int DHW = SZ * SZ * SZ;     // 4096000

typedef float vfloat4 __attribute__((ext_vector_type(4)));

__global__ __launch_bounds__(256, 3)
void warp_step_kernel(const float* __restrict__ src,
                      float* __restrict__ dst,
                      float inScale)
{
    // --- XCD-contiguous swizzle: 8000 blocks, 8 XCDs, 1000 contiguous each ---
    const int wg = (int)blockIdx.x;                 // 0..7999
    const int r  = (wg & 7) * 1000 + (wg >> 3);     // bijective (8000 % 8 == 0)
    const int h0  = r % SZ;                         // H-axis plane
    const int t   = r / SZ;                         // 0..49
    const int bat = t / 25;                         // batch
    const int tt  = t % 25;
    const int a0  = (tt % 5) * 32;                  // D-axis tile base
    const int c0  = (tt / 5) * 32;                  // W-axis tile base

    const float* __restrict__ vb = src + (size_t)bat * 3 * DHW;
    float*       __restrict__ db = dst + (size_t)bat * 3 * DHW;

    // tile[ch][w_local][d_local], stride 33 -> conflict-free in both phases
    __shared__ float tile[3][32][33];

    const int tid = (int)threadIdx.x;

    // --- phase 1: stage own-voxel v tile (scaled), float4 coalesced reads ---
    {
        const int q  = (tid & 7) << 2;   // float4 start within row (w_local)
        const int r0 = tid >> 3;         // 0..31 -> d_local; p -> channel
        #pragma unroll
        for (int p = 0; p < 3; ++p) {
            const vfloat4 vv = *reinterpret_cast<const vfloat4*>(
                &vb[p * DHW + (a0 + r0) * HW + h0 * SZ + c0 + q]);
            tile[p][q + 0][r0] = vv.x * inScale;
            tile[p][q + 1][r0] = vv.y * inScale;
            tile[p][q + 2][r0] = vv.z * inScale;
            tile[p][q + 3][r0] = vv.w * inScale;
        }
    }
    __syncthreads();

    // --- phase 2: d-fast lanes; 4 samples/thread, fully staged ---
    const int a  = tid & 31;      // d_local  (lane-fast)
    const int cb = tid >> 5;      // 0..7     (w_local base)
    const float gx = (float)(a0 + a);   // d feeds grid_sample's x slot
    const float gy = (float)h0;         // h feeds y slot

    // stage A: all LDS reads
    float v0s[4], v1s[4], v2s[4];
    #pragma unroll
    for (int i = 0; i < 4; ++i) {
        const int c = cb + (i << 3);
        v0s[i] = tile[0][c][a];
        v1s[i] = tile[1][c][a];
        v2s[i] = tile[2][c][a];
    }

    // stage B: all coordinate/address/weight math
    int o00[4], o01[4], o10[4], o11[4], x0a[4], x1a[4];
    float wxs[4], w00s[4], w01s[4], w10s[4], w11s[4];
    #pragma unroll
    for (int i = 0; i < 4; ++i) {
        const int c = cb + (i << 3);
        const float gz = (float)(c0 + c);
        float ix = ((2.0f * ((gx + v0s[i]) / 159.0f - 0.5f) + 1.0f) * 160.0f - 1.0f) * 0.5f;
        float iy = ((2.0f * ((gy + v1s[i]) / 159.0f - 0.5f) + 1.0f) * 160.0f - 1.0f) * 0.5f;
        float iz = ((2.0f * ((gz + v2s[i]) / 159.0f - 0.5f) + 1.0f) * 160.0f - 1.0f) * 0.5f;
        ix = fminf(fmaxf(ix, 0.0f), 159.0f);
        iy = fminf(fmaxf(iy, 0.0f), 159.0f);
        iz = fminf(fmaxf(iz, 0.0f), 159.0f);
        const float fx = floorf(ix), fy = floorf(iy), fz = floorf(iz);
        const float wx = ix - fx, wy = iy - fy, wz = iz - fz;
        const int x0 = (int)fx, y0 = (int)fy, z0 = (int)fz;
        const int x1 = min(x0 + 1, SZ - 1);
        const int y1 = min(y0 + 1, SZ - 1);
        const int z1 = min(z0 + 1, SZ - 1);
        o00[i] = (z0 * SZ + y0) * SZ;
        o01[i] = (z0 * SZ + y1) * SZ;
        o10[i] = (z1 * SZ + y0) * SZ;
        o11[i] = (z1 * SZ + y1) * SZ;
        x0a[i] = x0; x1a[i] = x1;
        const float wy0 = 1.0f - wy, wz0 = 1.0f - wz;
        wxs[i]  = wx;
        w00s[i] = wz0 * wy0; w01s[i] = wz0 * wy;
        w10s[i] = wz  * wy0; w11s[i] = wz  * wy;
    }

    // stage C: issue ALL 96 gather loads (no LDS ops in between)
    float g[4][3][8];
    #pragma unroll
    for (int i = 0; i < 4; ++i) {
        #pragma unroll
        for (int ch = 0; ch < 3; ++ch) {
            const float* __restrict__ pc = vb + ch * DHW;
            g[i][ch][0] = pc[o00[i] + x0a[i]];
            g[i][ch][1] = pc[o00[i] + x1a[i]];
            g[i][ch][2] = pc[o01[i] + x0a[i]];
            g[i][ch][3] = pc[o01[i] + x1a[i]];
            g[i][ch][4] = pc[o10[i] + x0a[i]];
            g[i][ch][5] = pc[o10[i] + x1a[i]];
            g[i][ch][6] = pc[o11[i] + x0a[i]];
            g[i][ch][7] = pc[o11[i] + x1a[i]];
        }
    }

    // stage D: interpolate
    float res[4][3];
    #pragma unroll
    for (int i = 0; i < 4; ++i) {
        #pragma unroll
        for (int ch = 0; ch < 3; ++ch) {
            const float s00 = g[i][ch][0] + wxs[i] * (g[i][ch][1] - g[i][ch][0]);
            const float s01 = g[i][ch][2] + wxs[i] * (g[i][ch][3] - g[i][ch][2]);
            const float s10 = g[i][ch][4] + wxs[i] * (g[i][ch][5] - g[i][ch][4]);
            const float s11 = g[i][ch][6] + wxs[i] * (g[i][ch][7] - g[i][ch][6]);
            res[i][ch] = (s00 * w00s[i] + s01 * w01s[i])
                       + (s10 * w10s[i] + s11 * w11s[i]);
        }
    }

    // stage E: single LDS write-back (own slots only -> no cross-thread hazard)
    #pragma unroll
    for (int i = 0; i < 4; ++i) {
        const int c = cb + (i << 3);
        tile[0][c][a] = v0s[i] + res[i][0] * inScale;
        tile[1][c][a] = v1s[i] + res[i][1] * inScale;
        tile[2][c][a] = v2s[i] + res[i][2] * inScale;
    }
    __syncthreads();

    // --- phase 3: coalesced float4 nontemporal writes ---
    {
        const int q  = (tid & 7) << 2;
        const int r0 = tid >> 3;
        #pragma unroll
        for (int p = 0; p < 3; ++p) {
            vfloat4 vv;
            vv.x = tile[p][q + 0][r0];
            vv.y = tile[p][q + 1][r0];
            vv.z = tile[p][q + 2][r0];
            vv.w = tile[p][q + 3][r0];
            __builtin_nontemporal_store(vv, reinterpret_cast<vfloat4*>(
                &db[p * DHW + (a0 + r0) * HW + h0 * SZ + c0 + q]));
        }
    }
}

extern "C" void kernel_launch(void* const* d_in, const int* in_sizes, int n_in,
                              void* d_out, int out_size, void* d_ws, size_t ws_size,
                              hipStream_t stream)
{
    const float* vin = (const float*)d_in[0];
    float* out = (float*)d_out;
    float* ws  = (float*)d_ws;   // needs >= 2*3*160^3*4 = 98,304,000 bytes

    dim3 grid(8000), block(256);
    // 7 steps, ping-pong so the final result lands in d_out.
    warp_step_kernel<<<grid, block, 0, stream>>>(vin, out, 1.0f / 128.0f); // v1
    warp_step_kernel<<<grid, block, 0, stream>>>(out, ws,  1.0f);          // v2
    warp_step_kernel<<<grid, block, 0, stream>>>(ws,  out, 1.0f);          // v3
    warp_step_kernel<<<grid, block, 0, stream>>>(out, ws,  1.0f);          // v4
    warp_step_kernel<<<grid, block, 0, stream>>>(ws,  out, 1.0f);          // v5
    warp_step_kernel<<<grid, block, 0, stream>>>(out, ws,  1.0f);          // v6
    warp_step_kernel<<<grid, block, 0, stream>>>(ws,  out, 1.0f);          // v7
}